// Round 1
// baseline (164.883 us; speedup 1.0000x reference)
//
#include <hip/hip_runtime.h>

// 16-qubit variational-circuit simulator, B=128.
// Convention: qubit q <-> flat bit (15-q). Output out[b][i] = sum_j |amp_j|^2 * (1-2*bit_i(j)).
// State stored packed float2(re,im); all post-encoding gates are real -> re/im evolve identically.
//
// P0: locals = qubits 0..13 (RX+RY1 folded into product init for q0..14; qubit15 stays |0>).
//     Applies light-cone: CZ1, RY2{0..13}, CZ2, RY3{0..12}, ..., RY8{0..7}, CZ8-subset.
//     CZ_k subset in P0: pairs q in [0,14-k].
// P1: locals = flat bits 0..11 (qubits 4..15). Folds psi15 (RX+RY1 on q15), then
//     CZ1-rem, RY2{b0,b1}, CZ2-rem, ..., RY8{b0..b7}, CZ8-rem, then measurement.
//     CZ_k remainder: pairs q in [15-k,14]  <=> mask (1<<k)-1 over (j & j>>1).

#define DEV __device__ __forceinline__

DEV float2 cmul(float2 a, float2 b) {
    return make_float2(a.x * b.x - a.y * b.y, a.x * b.y + a.y * b.x);
}

DEV void bfly(float2& a0, float2& a1, float C, float S) {
    float2 t0 = a0, t1 = a1;
    a0.x = C * t0.x - S * t1.x;  a0.y = C * t0.y - S * t1.y;
    a1.x = S * t0.x + C * t1.x;  a1.y = S * t0.y + C * t1.y;
}

// psi_q = RY(theta1_q) * RX(x_q) * |0>  -> two complex components as float2(re,im)
DEV void make_psi(const float* x, const float* theta, int b, int q,
                  float2& p0, float2& p1) {
    float sa, ca, SA, CA;
    sincosf(0.5f * x[b * 16 + q], &sa, &ca);
    sincosf(0.5f * theta[q], &SA, &CA);   // RY layer 1 = theta[0*16+q]
    p0 = make_float2(CA * ca, SA * sa);
    p1 = make_float2(SA * ca, -CA * sa);
}

// ---------------- P0 ----------------
// grid 256 = batch(128) x v(=qubit14 bit). block 512 threads, 32 amps/thread.
// local index l = (r<<9)|(lane<<3)|w ; l bit i <-> qubit 13-i.
//   r (5b):    qubits 0..4   (b_q = (r>>(4-q))&1)
//   lane (6b): qubits 5..10  (b_q = (lane>>(10-q))&1)
//   w (3b):    qubits 11..13 (b_q = (w>>(13-q))&1)
// store: st[b][ (v<<14) | (r<<9) | tid ]   (tid = (w<<6)|lane)
__global__ __launch_bounds__(512) void qsim_p0(const float* __restrict__ x,
                                               const float* __restrict__ theta,
                                               float2* __restrict__ st) {
    const int bx = blockIdx.x;
    const int b = bx >> 1, v = bx & 1;
    const int tid = threadIdx.x;
    const int lane = tid & 63, w = tid >> 6;

    __shared__ float2 X[16][512];  // 64 KB exchange buffer (chunked)

    // ---- product init through RY1 ----
    float2 common = make_float2(1.f, 0.f);
#pragma unroll
    for (int q = 5; q <= 10; ++q) {
        float2 p0, p1; make_psi(x, theta, b, q, p0, p1);
        int bit = (lane >> (10 - q)) & 1;
        common = cmul(common, bit ? p1 : p0);
    }
#pragma unroll
    for (int q = 11; q <= 13; ++q) {
        float2 p0, p1; make_psi(x, theta, b, q, p0, p1);
        int bit = (w >> (13 - q)) & 1;
        common = cmul(common, bit ? p1 : p0);
    }
    {
        float2 p0, p1; make_psi(x, theta, b, 14, p0, p1);
        common = cmul(common, v ? p1 : p0);
    }
    float2 ps0[5], ps1[5];
#pragma unroll
    for (int q = 0; q < 5; ++q) make_psi(x, theta, b, q, ps0[q], ps1[q]);

    float2 a[32];
    {   // tree expand over reg qubits 0..4 (qubit q at r bit 4-q)
        float2 l1[2], l2[4], l3[8], l4[16];
        l1[0] = cmul(common, ps0[0]); l1[1] = cmul(common, ps1[0]);
#pragma unroll
        for (int i = 0; i < 2; ++i) { l2[2*i] = cmul(l1[i], ps0[1]); l2[2*i+1] = cmul(l1[i], ps1[1]); }
#pragma unroll
        for (int i = 0; i < 4; ++i) { l3[2*i] = cmul(l2[i], ps0[2]); l3[2*i+1] = cmul(l2[i], ps1[2]); }
#pragma unroll
        for (int i = 0; i < 8; ++i) { l4[2*i] = cmul(l3[i], ps0[3]); l4[2*i+1] = cmul(l3[i], ps1[3]); }
#pragma unroll
        for (int i = 0; i < 16; ++i) { a[2*i] = cmul(l4[i], ps0[4]); a[2*i+1] = cmul(l4[i], ps1[4]); }
    }

    // ---- CZ sign machinery ----
    // A = (r<<10)|(lane<<4)|(w<<1)|v ; A bit z <-> qubit 14-z. B = A&(A>>1); B bit t <-> CZ pair q=13-t.
    // P0 CZ_k: pairs q in [0,14-k] -> B bits [k-1,13].
    const unsigned Athr = ((unsigned)lane << 4) | ((unsigned)w << 1) | (unsigned)v;
    const unsigned Bthr = (Athr & (Athr >> 1)) & 0x1FFu;  // B bits 0..8 (thread-fixed)
    unsigned G = 0;                                        // bit r = parity of B bits 9..13
#pragma unroll
    for (int r = 0; r < 32; ++r) G |= ((unsigned)(__popc(r & (r >> 1)) & 1)) << r;
    if (lane & 32) G ^= 0xAAAAAAAAu;  // B9 = lane5 & r0

    auto czP0 = [&](int k) {
        unsigned basek = (unsigned)(__popc(Bthr >> (k - 1)) & 1);
        unsigned W = basek ? ~G : G;
#pragma unroll
        for (int r = 0; r < 32; ++r) {
            unsigned sg = ((W >> r) & 1u) << 31;
            a[r].x = __uint_as_float(__float_as_uint(a[r].x) ^ sg);
            a[r].y = __uint_as_float(__float_as_uint(a[r].y) ^ sg);
        }
    };

    czP0(1);

    for (int k = 2; k <= 8; ++k) {
        const int qmax = 15 - k;
        // reg gates q=0..4
#pragma unroll
        for (int q = 0; q < 5; ++q) {
            float S, C; sincosf(0.5f * theta[(k - 1) * 16 + q], &S, &C);
            const int m = 1 << (4 - q);
#pragma unroll
            for (int r = 0; r < 32; ++r)
                if (!(r & m)) bfly(a[r], a[r | m], C, S);
        }
        // lane gates q=5..min(10,qmax)
        const int ql = qmax < 10 ? qmax : 10;
        for (int q = 5; q <= ql; ++q) {
            float S, C; sincosf(0.5f * theta[(k - 1) * 16 + q], &S, &C);
            const int lb = 10 - q;
            const int msk = 1 << lb;
            const float Sg = ((lane >> lb) & 1) ? S : -S;
#pragma unroll
            for (int r = 0; r < 32; ++r) {
                float px = __shfl_xor(a[r].x, msk);
                float py = __shfl_xor(a[r].y, msk);
                a[r].x = C * a[r].x + Sg * px;
                a[r].y = C * a[r].y + Sg * py;
            }
        }
        // wave gates q=11..min(13,qmax) via LDS (two 16-amp chunks)
        const int qw = qmax < 13 ? qmax : 13;
        for (int q = 11; q <= qw; ++q) {
            float S, C; sincosf(0.5f * theta[(k - 1) * 16 + q], &S, &C);
            const int wb = 13 - q;
            const int ptid = tid ^ (64 << wb);
            const float Sg = ((w >> wb) & 1) ? S : -S;
            for (int h = 0; h < 2; ++h) {
                __syncthreads();
#pragma unroll
                for (int i = 0; i < 16; ++i) X[i][tid] = a[h * 16 + i];
                __syncthreads();
#pragma unroll
                for (int i = 0; i < 16; ++i) {
                    float2 p = X[i][ptid];
                    a[h * 16 + i].x = C * a[h * 16 + i].x + Sg * p.x;
                    a[h * 16 + i].y = C * a[h * 16 + i].y + Sg * p.y;
                }
            }
        }
        czP0(k);
    }

    // ---- coalesced compact store ----
    float2* outp = st + b * 32768 + (v << 14);
#pragma unroll
    for (int r = 0; r < 32; ++r) outp[(r << 9) | tid] = a[r];
}

// ---------------- P1 ----------------
// grid 2048 = batch(128) x Q(=j[15:12], qubits 0..3). block 256, 16 amps/thread.
// j = (Q<<12)|(w1<<11)|(w0<<10)|(lane<<4)|m ; m bit B <-> flat bit B <-> qubit 15-B.
__global__ __launch_bounds__(256) void qsim_p1(const float* __restrict__ x,
                                               const float* __restrict__ theta,
                                               const float2* __restrict__ st,
                                               float* __restrict__ partials) {
    const int blk = blockIdx.x;
    const int b = blk >> 4, Q = blk & 15;
    const int tid = threadIdx.x;
    const int lane = tid & 63, wp = tid >> 6;
    const int w0 = wp & 1, w1 = wp >> 1;
    const int l0 = lane & 1;

    __shared__ float2 S4[4][512];   // seg = (v<<1)|w1seg, 16 KB
    __shared__ float red[4][16];

    const float2* base = st + b * 32768;
#pragma unroll
    for (int s = 0; s < 4; ++s) {
        const int v = s >> 1, wv = s & 1;
        const float4* src = reinterpret_cast<const float4*>(base + (v << 14) + (((Q << 1) | wv) << 9));
        reinterpret_cast<float4*>(&S4[s][0])[tid] = src[tid];
    }
    __syncthreads();

    // fold psi15 (RX+RY1 on qubit 15, flat bit 0); stored state had bit0=0 half only.
    float sa, ca, SA, CA;
    sincosf(0.5f * x[b * 16 + 15], &sa, &ca);
    sincosf(0.5f * theta[15], &SA, &CA);
    const float2 p0 = make_float2(CA * ca, SA * sa);
    const float2 p1 = make_float2(SA * ca, -CA * sa);

    float2 a[16];
#pragma unroll
    for (int mh = 0; mh < 8; ++mh) {          // m = 2*mh
        const int seg = ((mh & 1) << 1) | w1;  // v = m bit1 = mh&1
        const int idx = (l0 << 8) | ((mh >> 1) << 6) | (w0 << 5) | (lane >> 1);
        float2 s = S4[seg][idx];
        a[2 * mh]     = cmul(p0, s);
        a[2 * mh + 1] = cmul(p1, s);
    }

    // CZ remainder masks: sign_k(j) = parity(popc(j & (j>>1) & ((1<<k)-1)))
    unsigned PM[4] = {0, 0, 0, 0};  // per-amp parts, bits 0..3 of B' (B'3 = m3 & lane0)
#pragma unroll
    for (int m = 0; m < 16; ++m) {
        const int m0 = m & 1, m1 = (m >> 1) & 1, m2 = (m >> 2) & 1, m3 = (m >> 3) & 1;
        const unsigned Bm = (unsigned)((m0 & m1) | ((m1 & m2) << 1) | ((m2 & m3) << 2) | ((m3 & l0) << 3));
#pragma unroll
        for (int k = 1; k <= 4; ++k)
            PM[k - 1] |= ((unsigned)(__popc(Bm & ((1u << k) - 1)) & 1)) << m;
    }
    const int l1b = (lane >> 1) & 1, l2b = (lane >> 2) & 1, l3b = (lane >> 3) & 1, l4b = (lane >> 4) & 1;
    const unsigned Bhi = (unsigned)((l0 & l1b) | ((l1b & l2b) << 1) | ((l2b & l3b) << 2) | ((l3b & l4b) << 3));

    auto czP1 = [&](int k) {
        const unsigned pm = PM[(k < 4 ? k : 4) - 1];
        const unsigned thr = (k > 4) ? (unsigned)(__popc(Bhi & ((1u << (k - 4)) - 1)) & 1) : 0u;
        const unsigned W = thr ? ~pm : pm;
#pragma unroll
        for (int m = 0; m < 16; ++m) {
            unsigned sg = ((W >> m) & 1u) << 31;
            a[m].x = __uint_as_float(__float_as_uint(a[m].x) ^ sg);
            a[m].y = __uint_as_float(__float_as_uint(a[m].y) ^ sg);
        }
    };

    czP1(1);
    for (int k = 2; k <= 8; ++k) {
        // reg gates: flat bits 0..min(3,k-1), qubit = 15-B
#pragma unroll
        for (int B = 0; B < 4; ++B) {
            if (B < k) {
                float S, C; sincosf(0.5f * theta[(k - 1) * 16 + (15 - B)], &S, &C);
                const int mm = 1 << B;
#pragma unroll
                for (int m = 0; m < 16; ++m)
                    if (!(m & mm)) bfly(a[m], a[m | mm], C, S);
            }
        }
        // lane gates: flat bits 4..k-1 (lane bit B-4)
        const int bmax = k < 8 ? k : 8;
        for (int B = 4; B < bmax; ++B) {
            float S, C; sincosf(0.5f * theta[(k - 1) * 16 + (15 - B)], &S, &C);
            const int lb = B - 4;
            const int msk = 1 << lb;
            const float Sg = ((lane >> lb) & 1) ? S : -S;
#pragma unroll
            for (int m = 0; m < 16; ++m) {
                float px = __shfl_xor(a[m].x, msk);
                float py = __shfl_xor(a[m].y, msk);
                a[m].x = C * a[m].x + Sg * px;
                a[m].y = C * a[m].y + Sg * py;
            }
        }
        czP1(k);
    }

    // ---- measurement ----
    float Ssum = 0.f, S1[4] = {0.f, 0.f, 0.f, 0.f};
#pragma unroll
    for (int m = 0; m < 16; ++m) {
        float pm = a[m].x * a[m].x + a[m].y * a[m].y;
        Ssum += pm;
#pragma unroll
        for (int bb = 0; bb < 4; ++bb)
            if (m & (1 << bb)) S1[bb] += pm;
    }
    float vals[16];
#pragma unroll
    for (int i = 0; i < 4; ++i) vals[i] = Ssum - 2.f * S1[i];
#pragma unroll
    for (int i = 4; i < 10; ++i) vals[i] = ((lane >> (i - 4)) & 1) ? -Ssum : Ssum;
    vals[10] = w0 ? -Ssum : Ssum;
    vals[11] = w1 ? -Ssum : Ssum;
#pragma unroll
    for (int i = 12; i < 16; ++i) vals[i] = ((Q >> (i - 12)) & 1) ? -Ssum : Ssum;

#pragma unroll
    for (int i = 0; i < 16; ++i) {
#pragma unroll
        for (int d = 32; d >= 1; d >>= 1) vals[i] += __shfl_xor(vals[i], d);
    }
    if (lane == 0) {
#pragma unroll
        for (int i = 0; i < 16; ++i) red[wp][i] = vals[i];
    }
    __syncthreads();
    if (tid < 16) {
        float r = red[0][tid] + red[1][tid] + red[2][tid] + red[3][tid];
        partials[(b * 16 + Q) * 16 + tid] = r;
    }
}

// ---------------- P2: reduce partials over the 16 Q-tiles ----------------
__global__ void qsim_p2(const float* __restrict__ partials, float* __restrict__ out) {
    const int idx = blockIdx.x * 256 + threadIdx.x;  // 2048 outputs
    if (idx < 2048) {
        const int b = idx >> 4, i = idx & 15;
        float s = 0.f;
#pragma unroll
        for (int Qt = 0; Qt < 16; ++Qt) s += partials[(b * 16 + Qt) * 16 + i];
        out[idx] = s;
    }
}

extern "C" void kernel_launch(void* const* d_in, const int* in_sizes, int n_in,
                              void* d_out, int out_size, void* d_ws, size_t ws_size,
                              hipStream_t stream) {
    const float* x = (const float*)d_in[0];       // [128,16]
    const float* theta = (const float*)d_in[1];   // [128]
    float* out = (float*)d_out;                   // [128,16]
    float2* st = (float2*)d_ws;                   // 128 * 32768 float2 = 32 MB
    float* partials = (float*)((char*)d_ws + (size_t)128 * 32768 * sizeof(float2));  // 128 KB

    qsim_p0<<<256, 512, 0, stream>>>(x, theta, st);
    qsim_p1<<<2048, 256, 0, stream>>>(x, theta, st, partials);
    qsim_p2<<<8, 256, 0, stream>>>(partials, out);
}

// Round 2
// 138.821 us; speedup vs baseline: 1.1877x; 1.1877x over previous
//
#include <hip/hip_runtime.h>

// 16-qubit variational-circuit simulator, B=128, re/im split into independent
// real states (all post-encoding gates are real; Z-expectation is additive in
// |re|^2 and |im|^2).
//
// Convention (proven in round 0): qubit q <-> flat bit (15-q).
// ws layout (floats): st[128*2*32768] @0 (32MB, [b][comp][compact amp, q15 dropped]),
// partials[2048*16] @8388608, tsc[128 float2] @+32768, psit[2048 float4] after.

#define DEV __device__ __forceinline__

DEV float2 cmul(float2 a, float2 b) {
    return make_float2(a.x * b.x - a.y * b.y, a.x * b.y + a.y * b.x);
}

// ---------------- precompute tables ----------------
// tsc[g] = (cos(theta_g/2), sin(theta_g/2));  psit[b*16+q] = (p0.re,p0.im,p1.re,p1.im)
// with psi = RY(theta_{layer1,q}) * RX(x_bq) * |0>.
__global__ void qsim_pre(const float* __restrict__ x, const float* __restrict__ theta,
                         float2* __restrict__ tsc, float4* __restrict__ psit) {
    const int t = blockIdx.x * 256 + threadIdx.x;
    if (t < 128) {
        float S, C; sincosf(0.5f * theta[t], &S, &C);
        tsc[t] = make_float2(C, S);
    }
    if (t < 2048) {
        const int b = t >> 4, q = t & 15;
        float sa, ca, SA, CA;
        sincosf(0.5f * x[b * 16 + q], &sa, &ca);
        sincosf(0.5f * theta[q], &SA, &CA);
        psit[t] = make_float4(CA * ca, SA * sa, SA * ca, -CA * sa);
    }
}

// ---------------- P0 ----------------
// grid 512 = b(128) x v(qubit14) x c(component). block 512, 32 floats/thread.
// local l = (r<<9)|(lane<<3)|w: r<->q0..4, lane<->q5..10, w<->q11..13.
// Light cone: RY_k applied for q <= 15-k; CZ_k pairs q in [0,14-k].
__global__ __launch_bounds__(512) void qsim_p0(const float4* __restrict__ psit,
                                               const float2* __restrict__ tsc,
                                               float* __restrict__ st) {
    const int bx = blockIdx.x;
    const int b = bx >> 2, v = (bx >> 1) & 1, c = bx & 1;
    const int tid = threadIdx.x;
    const int lane = tid & 63, w = tid >> 6;

    __shared__ float X[16][512];  // 32 KB exchange

    // ---- product init through RY1 (table-driven) ----
    const float4* pb = psit + b * 16;
    float2 common = make_float2(1.f, 0.f);
#pragma unroll
    for (int q = 5; q <= 10; ++q) {
        float4 p = pb[q];
        int bit = (lane >> (10 - q)) & 1;
        common = cmul(common, bit ? make_float2(p.z, p.w) : make_float2(p.x, p.y));
    }
#pragma unroll
    for (int q = 11; q <= 13; ++q) {
        float4 p = pb[q];
        int bit = (w >> (13 - q)) & 1;
        common = cmul(common, bit ? make_float2(p.z, p.w) : make_float2(p.x, p.y));
    }
    {
        float4 p = pb[14];
        common = cmul(common, v ? make_float2(p.z, p.w) : make_float2(p.x, p.y));
    }
    float2 ps0[5], ps1[5];
#pragma unroll
    for (int q = 0; q < 5; ++q) {
        float4 p = pb[q];
        ps0[q] = make_float2(p.x, p.y);
        ps1[q] = make_float2(p.z, p.w);
    }

    float a[32];
    {
        float2 l1[2], l2[4], l3[8], l4[16];
        l1[0] = cmul(common, ps0[0]); l1[1] = cmul(common, ps1[0]);
#pragma unroll
        for (int i = 0; i < 2; ++i) { l2[2*i] = cmul(l1[i], ps0[1]); l2[2*i+1] = cmul(l1[i], ps1[1]); }
#pragma unroll
        for (int i = 0; i < 4; ++i) { l3[2*i] = cmul(l2[i], ps0[2]); l3[2*i+1] = cmul(l2[i], ps1[2]); }
#pragma unroll
        for (int i = 0; i < 8; ++i) { l4[2*i] = cmul(l3[i], ps0[3]); l4[2*i+1] = cmul(l3[i], ps1[3]); }
#pragma unroll
        for (int i = 0; i < 16; ++i) {
            float2 e0 = cmul(l4[i], ps0[4]), e1 = cmul(l4[i], ps1[4]);
            a[2*i]   = c ? e0.y : e0.x;
            a[2*i+1] = c ? e1.y : e1.x;
        }
    }

    // ---- CZ sign machinery (proven round 0) ----
    const unsigned Athr = ((unsigned)lane << 4) | ((unsigned)w << 1) | (unsigned)v;
    const unsigned Bthr = (Athr & (Athr >> 1)) & 0x1FFu;
    unsigned G = 0;
#pragma unroll
    for (int r = 0; r < 32; ++r) G |= ((unsigned)(__popc(r & (r >> 1)) & 1)) << r;
    if (lane & 32) G ^= 0xAAAAAAAAu;

    auto czP0 = [&](int k) {
        unsigned basek = (unsigned)(__popc(Bthr >> (k - 1)) & 1);
        unsigned Wm = basek ? ~G : G;
#pragma unroll
        for (int r = 0; r < 32; ++r) {
            unsigned sg = ((Wm >> r) & 1u) << 31;
            a[r] = __uint_as_float(__float_as_uint(a[r]) ^ sg);
        }
    };

    czP0(1);

    for (int k = 2; k <= 8; ++k) {
        const int qmax = 15 - k;
        // reg gates q=0..4
#pragma unroll
        for (int q = 0; q < 5; ++q) {
            float2 cs = tsc[(k - 1) * 16 + q];
            const float C = cs.x, S = cs.y;
            const int m = 1 << (4 - q);
#pragma unroll
            for (int r = 0; r < 32; ++r)
                if (!(r & m)) {
                    float t0 = a[r], t1 = a[r | m];
                    a[r]     = C * t0 - S * t1;
                    a[r | m] = S * t0 + C * t1;
                }
        }
        // lane gates q=5..min(10,qmax)
        const int ql = qmax < 10 ? qmax : 10;
        for (int q = 5; q <= ql; ++q) {
            float2 cs = tsc[(k - 1) * 16 + q];
            const float C = cs.x, S = cs.y;
            const int lb = 10 - q;
            const int msk = 1 << lb;
            const float Sg = ((lane >> lb) & 1) ? S : -S;
#pragma unroll
            for (int r = 0; r < 32; ++r) {
                float p = __shfl_xor(a[r], msk);
                a[r] = C * a[r] + Sg * p;
            }
        }
        // wave gates q=11..min(13,qmax) via LDS (two 16-reg chunks)
        const int qw = qmax < 13 ? qmax : 13;
        for (int q = 11; q <= qw; ++q) {
            float2 cs = tsc[(k - 1) * 16 + q];
            const float C = cs.x, S = cs.y;
            const int wb = 13 - q;
            const int ptid = tid ^ (64 << wb);
            const float Sg = ((w >> wb) & 1) ? S : -S;
            for (int h = 0; h < 2; ++h) {
                __syncthreads();
#pragma unroll
                for (int i = 0; i < 16; ++i) X[i][tid] = a[h * 16 + i];
                __syncthreads();
#pragma unroll
                for (int i = 0; i < 16; ++i) {
                    float p = X[i][ptid];
                    a[h * 16 + i] = C * a[h * 16 + i] + Sg * p;
                }
            }
        }
        czP0(k);
    }

    // compact coalesced store
    float* outp = st + (((size_t)(b * 2 + c)) << 15) + ((size_t)v << 14);
#pragma unroll
    for (int r = 0; r < 32; ++r) outp[(r << 9) | tid] = a[r];
}

// ---------------- P1 ----------------
// grid 2048 = b(128) x Q(j[15:12]). block 512: tid=(W<<6)|lane,
// W = (w1<<2)|(w0<<1)|c. j = (Q<<12)|(w1<<11)|(w0<<10)|(lane<<4)|m, m in [0,16).
// Each thread evolves component c of 16 amps.
__global__ __launch_bounds__(512) void qsim_p1(const float4* __restrict__ psit,
                                               const float2* __restrict__ tsc,
                                               const float* __restrict__ st,
                                               float* __restrict__ partials) {
    const int blk = blockIdx.x;
    const int b = blk >> 4, Q = blk & 15;
    const int tid = threadIdx.x;
    const int lane = tid & 63, W = tid >> 6;
    const int c = W & 1, w0 = (W >> 1) & 1, w1 = (W >> 2) & 1;
    const int l0 = lane & 1;

    __shared__ float S4[2][4][512];  // [comp][seg=(v<<1)|w1][512], 16 KB
    __shared__ float red[8][12];

#pragma unroll
    for (int t = 0; t < 8; ++t) {
        const int cin = t >> 2, s = t & 3;
        const int v = s >> 1, wv = s & 1;
        const float* src = st + (((size_t)(b * 2 + cin)) << 15) + (v << 14) + (((Q << 1) | wv) << 9);
        S4[cin][s][tid] = src[tid];
    }
    __syncthreads();

    const float4 p15 = psit[b * 16 + 15];  // psi on qubit 15 (flat bit 0)

    float a[16];
#pragma unroll
    for (int mh = 0; mh < 8; ++mh) {        // m = 2*mh
        const int seg = ((mh & 1) << 1) | w1;
        const int idx = (l0 << 8) | ((mh >> 1) << 6) | (w0 << 5) | (lane >> 1);
        const float sre = S4[0][seg][idx], sim = S4[1][seg][idx];
        if (c == 0) {
            a[2*mh]   = p15.x * sre - p15.y * sim;
            a[2*mh+1] = p15.z * sre - p15.w * sim;
        } else {
            a[2*mh]   = p15.x * sim + p15.y * sre;
            a[2*mh+1] = p15.z * sim + p15.w * sre;
        }
    }

    // CZ remainder (proven round 0): sign_k(j) = parity(popc(j & (j>>1) & ((1<<k)-1)))
    unsigned PM[4] = {0, 0, 0, 0};
#pragma unroll
    for (int m = 0; m < 16; ++m) {
        const int m0 = m & 1, m1 = (m >> 1) & 1, m2 = (m >> 2) & 1, m3 = (m >> 3) & 1;
        const unsigned Bm = (unsigned)((m0 & m1) | ((m1 & m2) << 1) | ((m2 & m3) << 2) | ((m3 & l0) << 3));
#pragma unroll
        for (int k = 1; k <= 4; ++k)
            PM[k - 1] |= ((unsigned)(__popc(Bm & ((1u << k) - 1)) & 1)) << m;
    }
    const int l1b = (lane >> 1) & 1, l2b = (lane >> 2) & 1, l3b = (lane >> 3) & 1, l4b = (lane >> 4) & 1;
    const unsigned Bhi = (unsigned)((l0 & l1b) | ((l1b & l2b) << 1) | ((l2b & l3b) << 2) | ((l3b & l4b) << 3));

    auto czP1 = [&](int k) {
        const unsigned pm = PM[(k < 4 ? k : 4) - 1];
        const unsigned thr = (k > 4) ? (unsigned)(__popc(Bhi & ((1u << (k - 4)) - 1)) & 1) : 0u;
        const unsigned Wm = thr ? ~pm : pm;
#pragma unroll
        for (int m = 0; m < 16; ++m) {
            unsigned sg = ((Wm >> m) & 1u) << 31;
            a[m] = __uint_as_float(__float_as_uint(a[m]) ^ sg);
        }
    };

    czP1(1);
    for (int k = 2; k <= 8; ++k) {
#pragma unroll
        for (int B = 0; B < 4; ++B) {
            if (B < k) {
                float2 cs = tsc[(k - 1) * 16 + (15 - B)];
                const float C = cs.x, S = cs.y;
                const int mm = 1 << B;
#pragma unroll
                for (int m = 0; m < 16; ++m)
                    if (!(m & mm)) {
                        float t0 = a[m], t1 = a[m | mm];
                        a[m]      = C * t0 - S * t1;
                        a[m | mm] = S * t0 + C * t1;
                    }
            }
        }
        const int bmax = k < 8 ? k : 8;
        for (int B = 4; B < bmax; ++B) {
            float2 cs = tsc[(k - 1) * 16 + (15 - B)];
            const float C = cs.x, S = cs.y;
            const int lb = B - 4;
            const int msk = 1 << lb;
            const float Sg = ((lane >> lb) & 1) ? S : -S;
#pragma unroll
            for (int m = 0; m < 16; ++m) {
                float p = __shfl_xor(a[m], msk);
                a[m] = C * a[m] + Sg * p;
            }
        }
        czP1(k);
    }

    // ---- measurement ----
    float Ssum = 0.f, S1[4] = {0.f, 0.f, 0.f, 0.f};
#pragma unroll
    for (int m = 0; m < 16; ++m) {
        float pm = a[m] * a[m];
        Ssum += pm;
#pragma unroll
        for (int bb = 0; bb < 4; ++bb)
            if (m & (1 << bb)) S1[bb] += pm;
    }
    // Walsh-style wave reduction: P = plain sum; Bv[d] = sum signed by lane bit d
    float P = Ssum;
    float Bv[6];
#pragma unroll
    for (int d = 0; d < 6; ++d) {
        float t = __shfl_xor(P, 1 << d);
        Bv[d] = ((lane >> d) & 1) ? (t - P) : (P - t);
        P += t;
#pragma unroll
        for (int e = 0; e < 6; ++e)
            if (e < d) Bv[e] += __shfl_xor(Bv[e], 1 << d);
    }
#pragma unroll
    for (int i = 0; i < 4; ++i)
#pragma unroll
        for (int d = 0; d < 6; ++d) S1[i] += __shfl_xor(S1[i], 1 << d);

    if (lane == 0) {
        red[W][0] = P;
#pragma unroll
        for (int d = 0; d < 6; ++d) red[W][1 + d] = Bv[d];
#pragma unroll
        for (int i = 0; i < 4; ++i) red[W][7 + i] = S1[i];
    }
    __syncthreads();
    if (tid < 16) {
        const int i = tid;
        float r = 0.f;
#pragma unroll
        for (int Wt = 0; Wt < 8; ++Wt) {
            const float A = red[Wt][0];
            if (i < 4)        r += A - 2.f * red[Wt][7 + i];
            else if (i < 10)  r += red[Wt][1 + (i - 4)];
            else if (i == 10) r += ((Wt >> 1) & 1) ? -A : A;
            else if (i == 11) r += ((Wt >> 2) & 1) ? -A : A;
            else              r += A;
        }
        if (i >= 12 && ((Q >> (i - 12)) & 1)) r = -r;
        partials[(blk << 4) + i] = r;
    }
}

// ---------------- P2 ----------------
__global__ void qsim_p2(const float* __restrict__ partials, float* __restrict__ out) {
    const int idx = blockIdx.x * 256 + threadIdx.x;  // 2048 outputs
    if (idx < 2048) {
        const int b = idx >> 4, i = idx & 15;
        float s = 0.f;
#pragma unroll
        for (int Qt = 0; Qt < 16; ++Qt) s += partials[(b * 16 + Qt) * 16 + i];
        out[idx] = s;
    }
}

extern "C" void kernel_launch(void* const* d_in, const int* in_sizes, int n_in,
                              void* d_out, int out_size, void* d_ws, size_t ws_size,
                              hipStream_t stream) {
    const float* x = (const float*)d_in[0];       // [128,16]
    const float* theta = (const float*)d_in[1];   // [128]
    float* out = (float*)d_out;                   // [128,16]
    float* ws = (float*)d_ws;
    float* st = ws;                               // 8388608 floats = 32 MB
    float* partials = ws + 8388608;               // 32768 floats = 128 KB
    float2* tsc = (float2*)(ws + 8388608 + 32768);        // 128 float2
    float4* psit = (float4*)(ws + 8388608 + 32768 + 256); // 2048 float4 (16B-aligned)

    qsim_pre<<<8, 256, 0, stream>>>(x, theta, tsc, psit);
    qsim_p0<<<512, 512, 0, stream>>>(psit, tsc, st);
    qsim_p1<<<2048, 512, 0, stream>>>(psit, tsc, st, partials);
    qsim_p2<<<8, 256, 0, stream>>>(partials, out);
}